// Round 13
// baseline (266.336 us; speedup 1.0000x reference)
//
#include <hip/hip_runtime.h>
#include <cstddef>

#define IN_CH 1024
#define NT    81
#define KGRID 7
#define NBINS 49
#define HH    100
#define WW    100
#define NPIX  (HH*WW)
#define NREG  1024
#define COLB  82            // gemm column group per bin: 81 real + 1 zero pad
#define NCOL  (NBINS*COLB)  // 4018 gemm columns (32 N-tiles of 128)
#define NPADW 4096          // 32 N-tiles (multiple of 8 XCDs)
#define SBIN  84            // sm per-bin stride in BYTES (int8), 4-aligned rows
#define SROWB (NBINS*SBIN)  // 4116 B per pixel row
#define NG    8             // pool tap-groups per region (8*98 = 784)
#define NSC   2560          // sm scale table floats (79*32 = 2528 used, padded)
#define PXB   ((NPIX + 31) / 32)        // 313 prep_x col-blocks
#define PXG   (PXB * (IN_CH / 128))     // 2504 prep_x blocks
#define PREPG (PXG + NPADW)             // + 4096 prep_w blocks

typedef unsigned short ushortT;
typedef unsigned char  u8;
typedef int i32x4 __attribute__((ext_vector_type(4)));

static __device__ __forceinline__ unsigned short f2bf(float f) {
    unsigned int u = __builtin_bit_cast(unsigned int, f);
    return (unsigned short)((u + 0x7fffu + ((u >> 16) & 1u)) >> 16);
}

// async global->LDS, 16B per lane; LDS dest = wave-uniform base + lane*16
static __device__ __forceinline__ void gld_lds16(const void* g, void* l) {
    __builtin_amdgcn_global_load_lds(
        (__attribute__((address_space(1))) void*)(unsigned long long)(uintptr_t)g,
        (__attribute__((address_space(3))) void*)(unsigned int)(unsigned long long)(uintptr_t)l,
        16, 0, 0);
}

// ---------- pass 0: per-pixel amax over 1024 channels -------------------------------
__global__ __launch_bounds__(256) void amax_x(const float* __restrict__ x,
                                              float* __restrict__ sxa,
                                              float* __restrict__ inv_sxa) {
    __shared__ float red[4][64];
    const int tid = threadIdx.x;
    const int pl = tid & 63, cg = tid >> 6;   // 4 channel groups
    const int p = blockIdx.x * 64 + pl;
    float am = 1e-30f;
    if (p < NPIX) {
        for (int c = cg; c < IN_CH; c += 4)
            am = fmaxf(am, fabsf(x[(size_t)c * NPIX + p]));
    }
    red[cg][pl] = am;
    __syncthreads();
    if (tid < 64) {
        const float m = fmaxf(fmaxf(red[0][tid], red[1][tid]),
                              fmaxf(red[2][tid], red[3][tid]));
        const int pp = blockIdx.x * 64 + tid;
        if (pp < NPIX) {
            sxa[pp]     = m * (1.0f / 127.0f);
            inv_sxa[pp] = 127.0f / m;
        }
    }
}

// ---------- fused prep: x -> xq int8 (P,C) row-scaled  |  conv_w -> Wq int8 ---------
__global__ __launch_bounds__(256) void prep_fused(const float* __restrict__ x,
                                                  u8* __restrict__ xq,
                                                  const float* __restrict__ inv_sxa,
                                                  const float* __restrict__ conv_w,
                                                  u8* __restrict__ Wq,
                                                  float* __restrict__ sxb) {
    __shared__ float tile[128][33];
    const int tid = threadIdx.x;
    const int bid = blockIdx.x;
    if (bid < PXG) {
        // ---- x part: 32 pix x 128 ch transpose + per-pixel int8 quantize ----
        const int p0 = (bid % PXB) * 32;
        const int c0 = (bid / PXB) * 128;
        const int pl = tid & 31;
        const int cg = tid >> 5;          // 0..7
        const int p = p0 + pl;
#pragma unroll
        for (int it = 0; it < 16; ++it) {
            const int c = it * 8 + cg;
            tile[c][pl] = (p < NPIX) ? x[(size_t)(c0 + c) * NPIX + p] : 0.0f;
        }
        __syncthreads();
        const int pix = tid >> 3;         // 0..31
        const int cb  = (tid & 7) * 16;   // 0..112
        const int pp = p0 + pix;
        if (pp < NPIX) {
            const float inv = inv_sxa[pp];
            uint4 pk;
            unsigned int w[4];
#pragma unroll
            for (int q = 0; q < 4; ++q) {
                unsigned int acc = 0;
#pragma unroll
                for (int j = 0; j < 4; ++j) {
                    const int v = __float2int_rn(tile[cb + q * 4 + j][pix] * inv);
                    acc |= ((unsigned int)(v & 0xff)) << (j * 8);
                }
                w[q] = acc;
            }
            pk.x = w[0]; pk.y = w[1]; pk.z = w[2]; pk.w = w[3];
            *(uint4*)(xq + (size_t)pp * IN_CH + c0 + cb) = pk;
        }
    } else {
        // ---- W part: one row n = bin*82+t; in-block amax -> int8 quantize ----
        const int row = bid - PXG;
        const int bin = row / COLB;
        const int t   = row - bin * COLB;
        const int c   = tid * 4;
        float4 v; v.x = 0.f; v.y = 0.f; v.z = 0.f; v.w = 0.f;
        if (bin < NBINS && t < NT)
            v = *(const float4*)(conv_w + ((size_t)(t * NBINS + bin)) * IN_CH + c);
        float am = fmaxf(fmaxf(fabsf(v.x), fabsf(v.y)), fmaxf(fabsf(v.z), fabsf(v.w)));
        float* red = (float*)tile;
        red[tid] = am;
        __syncthreads();
#pragma unroll
        for (int s = 128; s > 0; s >>= 1) {
            if (tid < s) red[tid] = fmaxf(red[tid], red[tid + s]);
            __syncthreads();
        }
        const float amax = fmaxf(red[0], 1e-30f);
        const float inv  = 127.0f / amax;
        if (tid == 0) sxb[row] = amax * (1.0f / 127.0f);
        const int q0 = __float2int_rn(v.x * inv);
        const int q1 = __float2int_rn(v.y * inv);
        const int q2 = __float2int_rn(v.z * inv);
        const int q3 = __float2int_rn(v.w * inv);
        const unsigned int pk = (unsigned int)(q0 & 0xff) | ((unsigned int)(q1 & 0xff) << 8) |
                                ((unsigned int)(q2 & 0xff) << 16) | ((unsigned int)(q3 & 0xff) << 24);
        *(unsigned int*)(Wq + (size_t)row * IN_CH + c) = pk;
    }
}

// ---------- GEMM int8: sm int8[pix][bin*84+t], scales[pt*32+nt] ---------------------
// 128x128 tile, BK=64B, 16 iters, mfma_i32_16x16x64_i8 (2x bf16 rate).
// LDS = 1KB tiles [(kgroup*16+m)*16B] -> fragment read is base+lane*16 (conflict-free,
// DMA-expressible). Epilogue: (float)acc * sxa[p] * sxb[n], then block-amax int8 sm.
__global__ __launch_bounds__(256) void gemm_sm(const u8* __restrict__ xq,
                                               const u8* __restrict__ Wq,
                                               const float* __restrict__ sxa,
                                               const float* __restrict__ sxb,
                                               u8* __restrict__ sm,
                                               float* __restrict__ scales) {
    __shared__ u8 a_lds[8192];   // 8 tiles of 1KB: rows 16t..16t+15
    __shared__ u8 b_lds[8192];
    const int tid  = threadIdx.x;
    const int lane = tid & 63;
    const int w    = tid >> 6;
    const int wm   = w & 1;
    const int wn   = w >> 1;
    const int n0   = blockIdx.x * 128;    // 0..31 tiles (mult of 8)
    const int p0   = blockIdx.y * 128;    // 0..78 tiles

    // staging: lane -> (m = lane&15 row-in-16, g = lane>>4 k-chunk of 16B)
    const int m  = lane & 15;
    const int g  = lane >> 4;
    int ar0 = p0 + w * 32 + m;       if (ar0 > NPIX - 1) ar0 = NPIX - 1;
    int ar1 = p0 + w * 32 + 16 + m;  if (ar1 > NPIX - 1) ar1 = NPIX - 1;
    const u8* ag0 = xq + (size_t)ar0 * IN_CH + g * 16;
    const u8* ag1 = xq + (size_t)ar1 * IN_CH + g * 16;
    const u8* bg0 = Wq + (size_t)(n0 + w * 32 + m) * IN_CH + g * 16;
    const u8* bg1 = Wq + (size_t)(n0 + w * 32 + 16 + m) * IN_CH + g * 16;
    u8* al0 = a_lds + (w * 2) * 1024 + lane * 16;
    u8* al1 = a_lds + (w * 2 + 1) * 1024 + lane * 16;
    u8* bl0 = b_lds + (w * 2) * 1024 + lane * 16;
    u8* bl1 = b_lds + (w * 2 + 1) * 1024 + lane * 16;

    i32x4 acc[4][4];
#pragma unroll
    for (int mt = 0; mt < 4; ++mt)
#pragma unroll
        for (int nt = 0; nt < 4; ++nt) acc[mt][nt] = (i32x4){0, 0, 0, 0};

    for (int kc = 0; kc < IN_CH / 64; ++kc) {     // 16 iterations
        __syncthreads();
        gld_lds16(ag0, al0);
        gld_lds16(ag1, al1);
        gld_lds16(bg0, bl0);
        gld_lds16(bg1, bl1);
        ag0 += 64; ag1 += 64; bg0 += 64; bg1 += 64;
        __syncthreads();

        i32x4 af[4], bf[4];
#pragma unroll
        for (int mt = 0; mt < 4; ++mt)
            af[mt] = *(const i32x4*)(a_lds + (wm * 4 + mt) * 1024 + lane * 16);
#pragma unroll
        for (int nt = 0; nt < 4; ++nt)
            bf[nt] = *(const i32x4*)(b_lds + (wn * 4 + nt) * 1024 + lane * 16);
#pragma unroll
        for (int mt = 0; mt < 4; ++mt)
#pragma unroll
            for (int nt = 0; nt < 4; ++nt)
                acc[mt][nt] = __builtin_amdgcn_mfma_i32_16x16x64_i8(af[mt], bf[nt], acc[mt][nt], 0, 0, 0);
    }

    // ---- rescale factors ----
    const int prow_base = p0 + wm * 64 + (lane >> 4) * 4;
    const int ncol_base = n0 + wn * 64 + m;
    float sb4[4];
#pragma unroll
    for (int nt = 0; nt < 4; ++nt) sb4[nt] = sxb[ncol_base + nt * 16];
    float sa4[4][4];
#pragma unroll
    for (int mt = 0; mt < 4; ++mt)
#pragma unroll
        for (int rg = 0; rg < 4; ++rg) {
            int p = prow_base + mt * 16 + rg;
            if (p > NPIX - 1) p = NPIX - 1;
            sa4[mt][rg] = sxa[p];
        }

    // ---- block amax (reuse a_lds as float scratch) ----
    float am = 0.0f;
#pragma unroll
    for (int mt = 0; mt < 4; ++mt)
#pragma unroll
        for (int nt = 0; nt < 4; ++nt)
#pragma unroll
            for (int rg = 0; rg < 4; ++rg)
                am = fmaxf(am, fabsf((float)acc[mt][nt][rg] * sa4[mt][rg] * sb4[nt]));
    __syncthreads();
    float* red = (float*)a_lds;
    red[tid] = am;
    __syncthreads();
#pragma unroll
    for (int s = 128; s > 0; s >>= 1) {
        if (tid < s) red[tid] = fmaxf(red[tid], red[tid + s]);
        __syncthreads();
    }
    const float amax = fmaxf(red[0], 1e-30f);
    const float inv  = 127.0f / amax;
    if (tid == 0) scales[blockIdx.y * 32 + blockIdx.x] = amax * (1.0f / 127.0f);

    // ---- quantize + store: n = bin*82+t -> byte offset n + 2*(n/82) ----
    int  coloff[4];
    bool cok[4];
#pragma unroll
    for (int nt = 0; nt < 4; ++nt) {
        const int n = ncol_base + nt * 16;
        cok[nt] = (n < NCOL);
        coloff[nt] = n + 2 * (n / COLB);
    }
#pragma unroll
    for (int mt = 0; mt < 4; ++mt) {
#pragma unroll
        for (int rg = 0; rg < 4; ++rg) {
            const int p = prow_base + mt * 16 + rg;
            if (p < NPIX) {
                u8* rowp = sm + (size_t)p * SROWB;
#pragma unroll
                for (int nt = 0; nt < 4; ++nt)
                    if (cok[nt]) {
                        const float fv = (float)acc[mt][nt][rg] * sa4[mt][rg] * sb4[nt];
                        const int q = __float2int_rn(fv * inv);
                        rowp[coloff[nt]] = (u8)(signed char)q;
                    }
            }
        }
    }
}

// ---------- pooling (round-12 proven): 16B/lane gathers, 10 taps per wave-load ------
__global__ __launch_bounds__(256) void pool_kernel(const u8* __restrict__ sm,
                                                   const float* __restrict__ scales,
                                                   const float* __restrict__ regions,
                                                   const float* __restrict__ conv_b,
                                                   float* __restrict__ out) {
    __shared__ int   rowo[28]; __shared__ float roww[28];
    __shared__ int   coli[28]; __shared__ float colw[28];
    __shared__ int   pofs[120];
    __shared__ float pw[120];
    __shared__ int   pptb[120];   // (pix>>7)*32
    __shared__ int   pnb[120];    // bin*82
    __shared__ float part[40][100];
    const int tid = threadIdx.x;
    const int r = blockIdx.x;
    const int g = blockIdx.y;   // 0..7

    if (tid < 28) {
        const float4 reg = *(const float4*)(regions + (size_t)r * 4);
        const float top = (reg.x - reg.z * 0.5f) * (float)HH;
        const float bh  = reg.z * ((float)HH / (float)KGRID);
        const int u = tid >> 2, i = tid & 3;
        const int s = i >> 1, hi = i & 1;
        float y = top + ((float)u + ((float)s + 0.5f) * 0.5f) * bh;
        y = fminf(fmaxf(y, 0.0f), (float)(HH - 1));
        const float y0f = floorf(y);
        const int y0 = (int)y0f;
        const float wy1 = y - y0f;
        rowo[tid] = (hi ? min(y0 + 1, HH - 1) : y0) * WW;
        roww[tid] = hi ? wy1 : (1.0f - wy1);
    } else if (tid >= 32 && tid < 60) {
        const float4 reg = *(const float4*)(regions + (size_t)r * 4);
        const float left = (reg.y - reg.w * 0.5f) * (float)WW;
        const float bw   = reg.w * ((float)WW / (float)KGRID);
        const int idx = tid - 32;
        const int v = idx >> 2, j = idx & 3;
        const int s = j >> 1, hi = j & 1;
        float xx = left + ((float)v + ((float)s + 0.5f) * 0.5f) * bw;
        xx = fminf(fmaxf(xx, 0.0f), (float)(WW - 1));
        const float x0f = floorf(xx);
        const int x0 = (int)x0f;
        const float wx1 = xx - x0f;
        coli[idx] = hi ? min(x0 + 1, WW - 1) : x0;
        colw[idx] = hi ? wx1 : (1.0f - wx1);
    }
    __syncthreads();
    if (tid < 120) {
        if (tid < 98) {                     // 8*98 == 784 exactly
            const int tt = g * 98 + tid;
            const int bin = tt >> 4, tap = tt & 15;
            const int u = bin / KGRID, v = bin - u * KGRID;
            const int i = tap >> 2, j = tap & 3;
            const int pix = rowo[u * 4 + i] + coli[v * 4 + j];
            pofs[tid] = pix * SROWB + bin * SBIN;     // BYTE offset, 4-aligned
            pw[tid]   = roww[u * 4 + i] * colw[v * 4 + j] * (1.0f / 196.0f);
            pptb[tid] = (pix >> 7) * 32;
            pnb[tid]  = bin * COLB;
        } else {                             // zero-weight padding taps
            pofs[tid] = 0;
            pw[tid]   = 0.0f;
            pptb[tid] = 0;
            pnb[tid]  = 0;
        }
    }
    __syncthreads();

    const int lane = tid & 63, w = tid >> 6;
    const int sub  = lane / 6;              // 0..9 active, lanes 60..63 idle
    const int cg   = lane - sub * 6;        // 0..5 -> channels cg*16..+15
    if (sub < 10) {
        const int str = w * 10 + sub;       // 0..39
        uint4 v[3];
#pragma unroll
        for (int it = 0; it < 3; ++it)
            v[it] = *(const uint4*)(sm + pofs[it * 40 + str] + cg * 16);

        float acc[16];
#pragma unroll
        for (int ch = 0; ch < 16; ++ch) acc[ch] = 0.0f;
#pragma unroll
        for (int it = 0; it < 3; ++it) {
            const int l  = it * 40 + str;
            const float wt = pw[l];
            const int nb  = pnb[l] + cg * 16;   // n of channel 0
            const int nt0 = nb >> 7;
            const int rr  = nb & 127;
            const float s0 = scales[pptb[l] + nt0];
            const float s1 = scales[pptb[l] + nt0 + 1];
            const float w0 = wt * s0, w1 = wt * s1;
            const unsigned int uu[4] = {v[it].x, v[it].y, v[it].z, v[it].w};
#pragma unroll
            for (int b = 0; b < 4; ++b) {
#pragma unroll
                for (int k = 0; k < 4; ++k) {
                    const int ch = b * 4 + k;
                    const int q = (int)(signed char)((uu[b] >> (k * 8)) & 0xff);
                    acc[ch] += ((rr < 128 - ch) ? w0 : w1) * (float)q;
                }
            }
        }
#pragma unroll
        for (int b = 0; b < 4; ++b) {
            float4 p4;
            p4.x = acc[b * 4]; p4.y = acc[b * 4 + 1];
            p4.z = acc[b * 4 + 2]; p4.w = acc[b * 4 + 3];
            *(float4*)&part[str][cg * 16 + b * 4] = p4;
        }
    }
    __syncthreads();
    if (tid < NT) {
        float vv = 0.f;
#pragma unroll
        for (int s = 0; s < 40; ++s) vv += part[s][tid];
        if (g == 0) {
            float bsum = 0.f;
            for (int bin = 0; bin < NBINS; ++bin) bsum += conv_b[tid * NBINS + bin];
            vv += bsum * (1.0f / (float)NBINS);
        }
        atomicAdd(out + (size_t)r * NT + tid, vv);
    }
}

// =======================  fallback path (round-1 kernel)  ==========================
__global__ __launch_bounds__(256) void xpose_kernel(const float* __restrict__ x,
                                                    float* __restrict__ xt) {
    __shared__ float tile[32][33];
    const int p0 = blockIdx.x * 32;
    const int c0 = blockIdx.y * 32;
    const int tx = threadIdx.x;
    const int ty = threadIdx.y;
#pragma unroll
    for (int k = 0; k < 32; k += 8) {
        const int p = p0 + tx;
        if (p < NPIX) tile[ty + k][tx] = x[(size_t)(c0 + ty + k) * NPIX + p];
    }
    __syncthreads();
#pragma unroll
    for (int k = 0; k < 32; k += 8) {
        const int p = p0 + ty + k;
        if (p < NPIX) xt[(size_t)p * IN_CH + (c0 + tx)] = tile[tx][ty + k];
    }
}

template <bool XPOSED>
__global__ __launch_bounds__(256) void psroi_kernel(
    const float* __restrict__ xsrc, const float* __restrict__ regions,
    const float* __restrict__ conv_w, const float* __restrict__ conv_b,
    float* __restrict__ out) {
    __shared__ float w_lds[32 * 96];
    __shared__ float g_lds[32 * 64];
    __shared__ int   rowoff[64][4];
    __shared__ float rowwf[64][4];
    __shared__ int   colidx[64][4];
    __shared__ float colwf[64][4];
    const int tid = threadIdx.x;
    const int bin = blockIdx.x >> 4;
    const int rg  = blockIdx.x & 15;
    const int u = bin / KGRID, v = bin % KGRID;
    const int r0 = rg * 64;
    if (tid < 64) {
        const float4 reg = *(const float4*)(regions + (size_t)(r0 + tid) * 4);
        const float top  = (reg.x - reg.z * 0.5f) * (float)HH;
        const float left = (reg.y - reg.w * 0.5f) * (float)WW;
        const float bh = reg.z * ((float)HH / (float)KGRID);
        const float bw = reg.w * ((float)WW / (float)KGRID);
        const float scale = 1.0f / 196.0f;
#pragma unroll
        for (int s = 0; s < 2; s++) {
            const float off = (s + 0.5f) * 0.5f;
            float yy = top + ((float)u + off) * bh;
            yy = fminf(fmaxf(yy, 0.0f), (float)(HH - 1));
            const float y0f = floorf(yy);
            const int y0 = (int)y0f;
            const float wy1 = yy - y0f;
            rowoff[tid][2 * s] = y0 * WW;
            rowoff[tid][2 * s + 1] = min(y0 + 1, HH - 1) * WW;
            rowwf[tid][2 * s] = (1.0f - wy1) * scale;
            rowwf[tid][2 * s + 1] = wy1 * scale;
            float xx = left + ((float)v + off) * bw;
            xx = fminf(fmaxf(xx, 0.0f), (float)(WW - 1));
            const float x0f = floorf(xx);
            const int x0 = (int)x0f;
            const float wx1 = xx - x0f;
            colidx[tid][2 * s] = x0;
            colidx[tid][2 * s + 1] = min(x0 + 1, WW - 1);
            colwf[tid][2 * s] = 1.0f - wx1;
            colwf[tid][2 * s + 1] = wx1;
        }
    }
    const int ri = tid & 15, tq = tid >> 4, rb = tid >> 2, cq = tid & 3;
    float acc[4][6];
#pragma unroll
    for (int m = 0; m < 4; m++)
#pragma unroll
        for (int k = 0; k < 6; k++) acc[m][k] = 0.0f;
    for (int chunk = 0; chunk < IN_CH / 32; chunk++) {
        const int c0 = chunk * 32;
        __syncthreads();
#pragma unroll
        for (int it = 0; it < 12; it++) {
            const int idx = it * 256 + tid;
            const int t = idx >> 5, c = idx & 31;
            float val = 0.0f;
            if (t < NT) val = conv_w[(size_t)(t * NBINS + bin) * IN_CH + c0 + c];
            w_lds[c * 96 + t] = val;
        }
        const int cbase = c0 + cq * 8;
        float g8[8];
#pragma unroll
        for (int cc = 0; cc < 8; cc++) g8[cc] = 0.0f;
#pragma unroll
        for (int i = 0; i < 4; i++) {
            const int ro = rowoff[rb][i];
            const float wy = rowwf[rb][i];
#pragma unroll
            for (int j = 0; j < 4; j++) {
                const int pix = ro + colidx[rb][j];
                const float wv = wy * colwf[rb][j];
                if (XPOSED) {
                    const float4* p = (const float4*)(xsrc + (size_t)pix * IN_CH + cbase);
                    const float4 a = p[0]; const float4 b = p[1];
                    g8[0] += wv * a.x; g8[1] += wv * a.y; g8[2] += wv * a.z; g8[3] += wv * a.w;
                    g8[4] += wv * b.x; g8[5] += wv * b.y; g8[6] += wv * b.z; g8[7] += wv * b.w;
                } else {
#pragma unroll
                    for (int cc = 0; cc < 8; cc++)
                        g8[cc] += wv * xsrc[(size_t)(cbase + cc) * NPIX + pix];
                }
            }
        }
#pragma unroll
        for (int cc = 0; cc < 8; cc++) g_lds[(cq * 8 + cc) * 64 + rb] = g8[cc];
        __syncthreads();
#pragma unroll 4
        for (int c = 0; c < 32; c++) {
            float wv[6];
#pragma unroll
            for (int k = 0; k < 6; k++) wv[k] = w_lds[c * 96 + tq * 6 + k];
            const float4 gq = *(const float4*)&g_lds[c * 64 + ri * 4];
            const float gm[4] = {gq.x, gq.y, gq.z, gq.w};
#pragma unroll
            for (int m = 0; m < 4; m++)
#pragma unroll
                for (int k = 0; k < 6; k++) acc[m][k] += gm[m] * wv[k];
        }
    }
    const float invK2 = 1.0f / 49.0f;
#pragma unroll
    for (int k = 0; k < 6; k++) {
        const int t = tq * 6 + k;
        if (t < NT) {
            const float bterm = conv_b[t * NBINS + bin] * invK2;
#pragma unroll
            for (int m = 0; m < 4; m++) {
                const int rr = r0 + ri * 4 + m;
                atomicAdd(&out[(size_t)rr * NT + t], acc[m][k] + bterm);
            }
        }
    }
}

extern "C" void kernel_launch(void* const* d_in, const int* in_sizes, int n_in,
                              void* d_out, int out_size, void* d_ws, size_t ws_size,
                              hipStream_t stream) {
    const float* x       = (const float*)d_in[0];
    const float* regions = (const float*)d_in[1];
    const float* conv_w  = (const float*)d_in[2];
    const float* conv_b  = (const float*)d_in[3];
    float* out = (float*)d_out;

    const size_t sz_xq  = (size_t)NPIX * IN_CH;          // 10,240,000
    const size_t sz_Wq  = (size_t)NPADW * IN_CH;         //  4,194,304
    const size_t sz_sxa = 10048 * sizeof(float);         //     40,192
    const size_t sz_isxa= 10048 * sizeof(float);         //     40,192
    const size_t sz_sxb = (size_t)NPADW * sizeof(float); //     16,384
    const size_t sz_sc  = (size_t)NSC * sizeof(float);   //     10,240
    const size_t sz_sm  = (size_t)NPIX * SROWB + 256;    // 41,160,256
    const size_t need   = sz_xq + sz_Wq + sz_sxa + sz_isxa + sz_sxb + sz_sc + sz_sm;

    if (ws_size >= need) {
        char* base = (char*)d_ws;
        u8*    xq      = (u8*)base;                       base += sz_xq;
        u8*    Wq      = (u8*)base;                       base += sz_Wq;
        float* sxa     = (float*)base;                    base += sz_sxa;
        float* inv_sxa = (float*)base;                    base += sz_isxa;
        float* sxb     = (float*)base;                    base += sz_sxb;
        float* scales  = (float*)base;                    base += sz_sc;
        u8*    sm      = (u8*)base;
        hipMemsetAsync(out, 0, (size_t)out_size * sizeof(float), stream);
        amax_x<<<dim3((NPIX + 63) / 64), 256, 0, stream>>>(x, sxa, inv_sxa);
        prep_fused<<<dim3(PREPG), 256, 0, stream>>>(x, xq, inv_sxa, conv_w, Wq, sxb);
        gemm_sm<<<dim3(NPADW / 128, (NPIX + 127) / 128), 256, 0, stream>>>(xq, Wq, sxa, sxb, sm, scales);
        pool_kernel<<<dim3(NREG, NG), 256, 0, stream>>>(sm, scales, regions, conv_b, out);
    } else {
        hipMemsetAsync(out, 0, (size_t)out_size * sizeof(float), stream);
        const size_t xt_bytes = (size_t)NPIX * IN_CH * sizeof(float);
        const dim3 mainGrid(NBINS * 16);
        if (ws_size >= xt_bytes) {
            float* xt = (float*)d_ws;
            xpose_kernel<<<dim3((NPIX + 31) / 32, IN_CH / 32), dim3(32, 8), 0, stream>>>(x, xt);
            psroi_kernel<true><<<mainGrid, 256, 0, stream>>>(xt, regions, conv_w, conv_b, out);
        } else {
            psroi_kernel<false><<<mainGrid, 256, 0, stream>>>(x, regions, conv_w, conv_b, out);
        }
    }
}